// Round 1
// baseline (1227.169 us; speedup 1.0000x reference)
//
#include <hip/hip_runtime.h>
#include <math.h>

#define Bc 4
#define Lc 4096
#define Dc 1024
#define Mtot (Bc*Lc)          // 16384 flattened tokens
#define NSEG 64               // segments per batch row
#define SEGLEN (Lc/NSEG)      // 64 tokens per segment

// ---------------------------------------------------------------------------
// K1: fused q/k GEMM + partial dot / |q|^2 / |k|^2 reduction.
//   q_t = Qw @ x_t, k_{t+1} = Kw @ x_{t+1};  cos[t] = q_t.k_{t+1}/(|q_t||k_{t+1}|)
// Grid: (Mtot/64) M-blocks x 2 N-halves = 512 WGs, block 256.
// Per WG: 64 tokens (+1 halo row), N-range 512 (looped in chunks of 128).
// Per thread: 8 contiguous rows x 4 strided cols, fp32 accumulate.
// parts layout: [half][3][Mtot]  (0=dot, 1=qn, 2=kn)
// ---------------------------------------------------------------------------
__global__ __launch_bounds__(256, 2)
void cos_gemm_kernel(const float* __restrict__ X,
                     const float* __restrict__ Qw,
                     const float* __restrict__ Kw,
                     float* __restrict__ parts)
{
    __shared__ float Xs[65][36];     // 65 rows x 32 (pad->36 floats, 16B-mult stride)
    __shared__ float Qs[128][36];
    __shared__ float Ks[128][36];

    const int tid    = threadIdx.x;
    const int mb     = blockIdx.x >> 1;
    const int half   = blockIdx.x & 1;
    const int t0     = mb * 64;
    const int tid_n  = tid & 31;     // 0..31 (column group, within-wave)
    const int tid_mg = tid >> 5;     // 0..7  (row group)
    const int row0   = tid_mg * 8;   // 8 contiguous rows + 1 halo

    float dsum[8], qn[8], kn[8];
    #pragma unroll
    for (int i = 0; i < 8; i++) { dsum[i] = 0.f; qn[i] = 0.f; kn[i] = 0.f; }

    float q_acc[8][4], k_acc[8][4];

    for (int n0 = 0; n0 < 512; n0 += 128) {
        const int nbase = half * 512 + n0;
        #pragma unroll
        for (int i = 0; i < 8; i++)
            #pragma unroll
            for (int j = 0; j < 4; j++) { q_acc[i][j] = 0.f; k_acc[i][j] = 0.f; }

        for (int k0 = 0; k0 < Dc; k0 += 32) {
            // ---- stage X tile: 65 rows x 32 cols (520 float4) ----
            for (int idx = tid; idx < 520; idx += 256) {
                const int r = idx >> 3, c = (idx & 7) * 4;
                int t = t0 + r; if (t >= Mtot) t = Mtot - 1;   // clamp halo at end
                const float4 v = *(const float4*)&X[t*Dc + k0 + c];
                *(float4*)&Xs[r][c] = v;
            }
            // ---- stage weight tiles: 128 rows x 32 cols each ----
            for (int idx = tid; idx < 1024; idx += 256) {
                const int r = idx >> 3, c = (idx & 7) * 4;
                const float4 vq = *(const float4*)&Qw[(nbase + r)*Dc + k0 + c];
                *(float4*)&Qs[r][c] = vq;
                const float4 vk = *(const float4*)&Kw[(nbase + r)*Dc + k0 + c];
                *(float4*)&Ks[r][c] = vk;
            }
            __syncthreads();

            for (int kq = 0; kq < 8; kq++) {
                float4 xv[9];
                #pragma unroll
                for (int i = 0; i < 9; i++)
                    xv[i] = *(const float4*)&Xs[row0 + i][kq*4];
                float4 qw[4], kw[4];
                #pragma unroll
                for (int j = 0; j < 4; j++) {
                    qw[j] = *(const float4*)&Qs[tid_n + 32*j][kq*4];
                    kw[j] = *(const float4*)&Ks[tid_n + 32*j][kq*4];
                }
                #pragma unroll
                for (int i = 0; i < 8; i++) {
                    const float4 xq = xv[i];       // q uses row i  (token t0+row0+i)
                    const float4 xk = xv[i+1];     // k uses row i+1 (token +1)
                    #pragma unroll
                    for (int j = 0; j < 4; j++) {
                        q_acc[i][j] += xq.x*qw[j].x;
                        q_acc[i][j] += xq.y*qw[j].y;
                        q_acc[i][j] += xq.z*qw[j].z;
                        q_acc[i][j] += xq.w*qw[j].w;
                        k_acc[i][j] += xk.x*kw[j].x;
                        k_acc[i][j] += xk.y*kw[j].y;
                        k_acc[i][j] += xk.z*kw[j].z;
                        k_acc[i][j] += xk.w*kw[j].w;
                    }
                }
            }
            __syncthreads();
        }
        // fold completed n-chunk (full K) into dot / norm partials
        #pragma unroll
        for (int i = 0; i < 8; i++)
            #pragma unroll
            for (int j = 0; j < 4; j++) {
                dsum[i] += q_acc[i][j] * k_acc[i][j];
                qn[i]   += q_acc[i][j] * q_acc[i][j];
                kn[i]   += k_acc[i][j] * k_acc[i][j];
            }
    }

    // reduce across the 32 tid_n lanes (same wave: lane = tid&63, tid_n = lane&31)
    #pragma unroll
    for (int m = 16; m >= 1; m >>= 1) {
        #pragma unroll
        for (int i = 0; i < 8; i++) {
            dsum[i] += __shfl_xor(dsum[i], m);
            qn[i]   += __shfl_xor(qn[i],   m);
            kn[i]   += __shfl_xor(kn[i],   m);
        }
    }
    if (tid_n == 0) {
        #pragma unroll
        for (int i = 0; i < 8; i++) {
            const int t = t0 + row0 + i;
            parts[half*3*Mtot + 0*Mtot + t] = dsum[i];
            parts[half*3*Mtot + 1*Mtot + t] = qn[i];
            parts[half*3*Mtot + 2*Mtot + t] = kn[i];
        }
    }
}

// ---------------------------------------------------------------------------
// K1b: combine halves, finalize cos[t] = dot / (max(|q|,1e-12)*max(|k|,1e-12))
// ---------------------------------------------------------------------------
__global__ void cos_fin_kernel(const float* __restrict__ parts,
                               float* __restrict__ cosv)
{
    const int t = blockIdx.x * 256 + threadIdx.x;
    if (t >= Mtot) return;
    const float dot = parts[0*Mtot + t] + parts[3*Mtot + t];
    const float qn  = parts[1*Mtot + t] + parts[4*Mtot + t];
    const float kn  = parts[2*Mtot + t] + parts[5*Mtot + t];
    const float nq = fmaxf(sqrtf(qn), 1e-12f);
    const float nk = fmaxf(sqrtf(kn), 1e-12f);
    cosv[t] = dot / (nq * nk);
}

// shared helper: build decay/mask for one segment (mirrors reference formula)
__device__ inline void build_seg_masks(const float* __restrict__ cosv,
                                       int b, int l0, float* dec, int* msk)
{
    const int tid = threadIdx.x;
    if (tid < SEGLEN) {
        const int l = l0 + tid;
        float p;
        if (l == 0) {
            p = 1.f;
        } else {
            const float c = cosv[b*Lc + l - 1];
            p = (1.f - c) * 0.5f;              // exact reference formula order
            p = fminf(fmaxf(p, 0.f), 1.f);
        }
        dec[tid] = 1.f - p;
        msk[tid] = (p > 0.5f) ? 1 : 0;
    }
    __syncthreads();
}

// ---------------------------------------------------------------------------
// K2: per-segment local affine scan: state_out = Aseg*state_in + Bseg
//     computed with state_in = 0 -> Bseg vector (D), Aseg scalar.
// Grid Bc*NSEG = 256, block 256 (4 d-elements / thread).
// ---------------------------------------------------------------------------
__global__ __launch_bounds__(256)
void seg_pass1_kernel(const float* __restrict__ X,
                      const float* __restrict__ cosv,
                      float* __restrict__ Aseg,
                      float* __restrict__ Bseg)
{
    __shared__ float dec[SEGLEN];
    __shared__ int   msk[SEGLEN];
    const int tid = threadIdx.x;
    const int b = blockIdx.x >> 6;
    const int s = blockIdx.x & 63;
    const int l0 = s * SEGLEN;
    build_seg_masks(cosv, b, l0, dec, msk);

    float4 st = make_float4(0.f, 0.f, 0.f, 0.f);
    float A = 1.f;
    const float* xb = X + (size_t)(b*Lc + l0)*Dc + tid*4;
    for (int i = 0; i < SEGLEN; i++) {
        if (msk[i]) {                      // block-uniform branch
            const float d = dec[i];
            const float w = 1.f - d;
            const float4 xv = *(const float4*)(xb + i*Dc);
            st.x = d*st.x + w*xv.x;
            st.y = d*st.y + w*xv.y;
            st.z = d*st.z + w*xv.z;
            st.w = d*st.w + w*xv.w;
            A *= d;
        }
    }
    *(float4*)&Bseg[(size_t)blockIdx.x*Dc + tid*4] = st;
    if (tid == 0) Aseg[blockIdx.x] = A;
}

// ---------------------------------------------------------------------------
// K3: sequential combine over segments: carry[s] = state entering segment s.
// Grid Bc = 4, block 256.
// ---------------------------------------------------------------------------
__global__ __launch_bounds__(256)
void seg_combine_kernel(const float* __restrict__ Aseg,
                        const float* __restrict__ Bseg,
                        const float* __restrict__ init_state,
                        float* __restrict__ carry)
{
    const int tid = threadIdx.x;
    const int b = blockIdx.x;
    float4 c = *(const float4*)&init_state[(size_t)b*Dc + tid*4];
    for (int s = 0; s < NSEG; s++) {
        const size_t idx = (size_t)(b*NSEG + s);
        *(float4*)&carry[idx*Dc + tid*4] = c;
        const float a = Aseg[idx];
        const float4 Bv = *(const float4*)&Bseg[idx*Dc + tid*4];
        c.x = a*c.x + Bv.x;
        c.y = a*c.y + Bv.y;
        c.z = a*c.z + Bv.z;
        c.w = a*c.w + Bv.w;
    }
}

// ---------------------------------------------------------------------------
// K4: final sweep with true carry: state = d*state + (1-d)*x on masked tokens;
//     out[l] = residual[l] + state  (STE coef == 1.0 in forward).
// Grid Bc*NSEG = 256, block 256.
// ---------------------------------------------------------------------------
__global__ __launch_bounds__(256)
void seg_pass2_kernel(const float* __restrict__ X,
                      const float* __restrict__ RES,
                      const float* __restrict__ cosv,
                      const float* __restrict__ carry,
                      float* __restrict__ OUT)
{
    __shared__ float dec[SEGLEN];
    __shared__ int   msk[SEGLEN];
    const int tid = threadIdx.x;
    const int b = blockIdx.x >> 6;
    const int s = blockIdx.x & 63;
    const int l0 = s * SEGLEN;
    build_seg_masks(cosv, b, l0, dec, msk);

    float4 st = *(const float4*)&carry[(size_t)blockIdx.x*Dc + tid*4];
    const size_t base = (size_t)(b*Lc + l0)*Dc + tid*4;
    const float* xb = X   + base;
    const float* rb = RES + base;
    float*       ob = OUT + base;
    for (int i = 0; i < SEGLEN; i++) {
        if (msk[i]) {
            const float d = dec[i];
            const float w = 1.f - d;
            const float4 xv = *(const float4*)(xb + (size_t)i*Dc);
            st.x = d*st.x + w*xv.x;
            st.y = d*st.y + w*xv.y;
            st.z = d*st.z + w*xv.z;
            st.w = d*st.w + w*xv.w;
        }
        const float4 rv = *(const float4*)(rb + (size_t)i*Dc);
        float4 ov;
        ov.x = rv.x + st.x;
        ov.y = rv.y + st.y;
        ov.z = rv.z + st.z;
        ov.w = rv.w + st.w;
        *(float4*)(ob + (size_t)i*Dc) = ov;
    }
}

// ---------------------------------------------------------------------------
extern "C" void kernel_launch(void* const* d_in, const int* in_sizes, int n_in,
                              void* d_out, int out_size, void* d_ws, size_t ws_size,
                              hipStream_t stream)
{
    const float* X    = (const float*)d_in[0];   // hidden_states (B,L,D)
    const float* RES  = (const float*)d_in[1];   // residual      (B,L,D)
    const float* QW   = (const float*)d_in[2];   // q_weight      (D,D)
    const float* KW   = (const float*)d_in[3];   // k_weight      (D,D)
    const float* INIT = (const float*)d_in[4];   // init_state    (B,D)
    float* OUT = (float*)d_out;

    // workspace layout (floats): parts[6*M] | cos[M] | Aseg[256] | Bseg[256*D] | carry[256*D]
    float* ws    = (float*)d_ws;
    float* parts = ws;
    float* cosv  = ws + 6*Mtot;
    float* Aseg  = ws + 7*Mtot;
    float* Bseg  = Aseg + Bc*NSEG;
    float* carry = Bseg + Bc*NSEG*Dc;

    cos_gemm_kernel   <<<(Mtot/64)*2, 256, 0, stream>>>(X, QW, KW, parts);
    cos_fin_kernel    <<<Mtot/256,    256, 0, stream>>>(parts, cosv);
    seg_pass1_kernel  <<<Bc*NSEG,     256, 0, stream>>>(X, cosv, Aseg, Bseg);
    seg_combine_kernel<<<Bc,          256, 0, stream>>>(Aseg, Bseg, INIT, carry);
    seg_pass2_kernel  <<<Bc*NSEG,     256, 0, stream>>>(X, RES, cosv, carry, OUT);
}

// Round 3
// 768.990 us; speedup vs baseline: 1.5958x; 1.5958x over previous
//
#include <hip/hip_runtime.h>
#include <math.h>

#define Bc 4
#define Lc 4096
#define Dc 1024
#define Mtot (Bc*Lc)          // 16384 flattened tokens
#define NSEG 64
#define SEGLEN (Lc/NSEG)      // 64

typedef __attribute__((ext_vector_type(8))) short short8;
typedef __attribute__((ext_vector_type(4))) float floatx4;
typedef unsigned short us;

// ---- workspace layout (bytes) — total ~10.3 MB ----
#define OFF_QHI   ((size_t)0)                       // 1024*1024 bf16 each
#define OFF_QLO   ((size_t)2097152)
#define OFF_KHI   ((size_t)4194304)
#define OFF_KLO   ((size_t)6291456)
#define OFF_PARTS ((size_t)8388608)                 // 3*Mtot f32 (dot,qn,kn)
#define OFF_FLAGS (OFF_PARTS + (size_t)196608)      // int count + 4096 idx
#define OFF_COSV  (OFF_FLAGS + (size_t)17408)       // Mtot f32
#define OFF_ASEG  (OFF_COSV + (size_t)65536)
#define OFF_BSEG  (OFF_ASEG + (size_t)1024)
#define OFF_CARRY (OFF_BSEG + (size_t)1048576)

// ---------------------------------------------------------------------------
// bf16 split helpers (RNE)
// ---------------------------------------------------------------------------
__device__ inline us f2bf(float x) {
    unsigned int u = __float_as_uint(x);
    u += 0x7FFFu + ((u >> 16) & 1u);
    return (us)(u >> 16);
}
__device__ inline float bf2f(us h) {
    return __uint_as_float(((unsigned int)h) << 16);
}

// zero parts[3*Mtot] + flags[0] (replaces hipMemsetAsync)
__global__ __launch_bounds__(256)
void zero_kernel(float* __restrict__ parts, int* __restrict__ flags)
{
    const int idx = blockIdx.x*256 + threadIdx.x;
    if (idx < 3*Mtot) parts[idx] = 0.f;
    if (idx == 0) flags[0] = 0;
}

__global__ __launch_bounds__(256)
void convert_w_kernel(const float* __restrict__ W,
                      us* __restrict__ Whi,
                      us* __restrict__ Wlo)
{
    const int e4 = blockIdx.x*256 + threadIdx.x;   // over 1024*256 float4s
    const float4 v = *(const float4*)&W[(size_t)e4*4];
    ushort4 h, l;
    h.x = f2bf(v.x); l.x = f2bf(v.x - bf2f(h.x));
    h.y = f2bf(v.y); l.y = f2bf(v.y - bf2f(h.y));
    h.z = f2bf(v.z); l.z = f2bf(v.z - bf2f(h.z));
    h.w = f2bf(v.w); l.w = f2bf(v.w - bf2f(h.w));
    *(ushort4*)&Whi[(size_t)e4*4] = h;
    *(ushort4*)&Wlo[(size_t)e4*4] = l;
}

// ---------------------------------------------------------------------------
// Fused MFMA GEMM with in-kernel X->bf16 hi/lo split (3-product emulation):
//   q_t = Qw.x_t, k'_t = Kw.x_{t+1}; accumulate dot/|q|^2/|k|^2 into
//   parts[3][Mtot] via atomics.
// Tiles: 128(M) x 128(N), BK=32, A-tile 129 rows (k-GEMM reads row+1).
// LDS: AsH/AsL 129x32 + 4 weight tiles 128x32 = 49,280 B.
// Grid 128*8 = 1024 WGs, block 256 (4 waves as 2x2 of 64x64).
// ---------------------------------------------------------------------------
#define AS1C const __attribute__((address_space(1))) void*
#define AS3P __attribute__((address_space(3))) void*

__global__ __launch_bounds__(256, 2)
void gemm_cos_kernel(const float* __restrict__ X,
                     const us* __restrict__ Qhi,
                     const us* __restrict__ Qlo,
                     const us* __restrict__ Khi,
                     const us* __restrict__ Klo,
                     float* __restrict__ parts)
{
    __shared__ __align__(16) us lds[24640];        // 49,280 B
    us* AsH = lds;                                  // 129 x 32
    us* AsL = lds + 4128;                           // 129 x 32
    us* Bs  = lds + 8256;                           // 4 x (128 x 32): qH,qL,kH,kL

    const int tid  = threadIdx.x;
    const int lane = tid & 63;
    const int wv   = tid >> 6;
    const int wm   = wv >> 1;
    const int wn   = wv & 1;
    const int bm   = blockIdx.x >> 3;
    const int bn   = blockIdx.x & 7;
    const int t0   = bm * 128;
    const int nb   = bn * 128;

    floatx4 accq[4][4], acck[4][4];
    const floatx4 zz = {0.f, 0.f, 0.f, 0.f};
    #pragma unroll
    for (int i = 0; i < 4; i++)
        #pragma unroll
        for (int j = 0; j < 4; j++) { accq[i][j] = zz; acck[i][j] = zz; }

    const us* Wt[4] = {Qhi, Qlo, Khi, Klo};

    const int lrow = lane & 15;
    const int lk   = (lane >> 4) << 3;   // 0,8,16,24 shorts

    for (int ch = 0; ch < 32; ++ch) {
        const int k0 = ch << 5;

        // ---- stage A: load fp32 X tile 129x32, split to hi/lo bf16 ----
        for (int g = tid; g < 1032; g += 256) {
            const int row = g >> 3, c4 = g & 7;
            int t = t0 + row; if (t >= Mtot) t = Mtot - 1;   // halo clamp (unused cos)
            const float4 v = *(const float4*)&X[(size_t)t*Dc + k0 + c4*4];
            ushort4 h, l;
            h.x = f2bf(v.x); l.x = f2bf(v.x - bf2f(h.x));
            h.y = f2bf(v.y); l.y = f2bf(v.y - bf2f(h.y));
            h.z = f2bf(v.z); l.z = f2bf(v.z - bf2f(h.z));
            h.w = f2bf(v.w); l.w = f2bf(v.w - bf2f(h.w));
            *(ushort4*)&AsH[row*32 + c4*4] = h;
            *(ushort4*)&AsL[row*32 + c4*4] = l;
        }
        // ---- stage B: 4 weight tiles 128x32 bf16 via global_load_lds ----
        #pragma unroll
        for (int it = 0; it < 8; ++it) {
            const int gb  = it*256 + wv*64;           // wave-uniform granule base
            const int g   = gb + lane;
            const int tile = g >> 9;                  // wave-uniform (64-run never crosses)
            const int gg  = g & 511;
            const int row = gg >> 2, col = (gg & 3) << 3;
            const us* gp = Wt[tile] + (size_t)(nb + row)*Dc + k0 + col;
            __builtin_amdgcn_global_load_lds((AS1C)gp, (AS3P)(Bs + gb*8), 16, 0, 0);
        }
        __syncthreads();

        short8 aq[4], ak[4];
        // hi A fragments (reused for both B-hi and B-lo phases)
        #pragma unroll
        for (int i = 0; i < 4; ++i) {
            const int r = wm*64 + i*16 + lrow;
            aq[i] = *(const short8*)&AsH[r*32 + lk];
            ak[i] = *(const short8*)&AsH[(r+1)*32 + lk];
        }
        #pragma unroll
        for (int pb = 0; pb < 2; ++pb) {              // pb=0: W-hi, pb=1: W-lo
            const us* bq = Bs + (pb ? 4096 : 0);
            const us* bk = Bs + (pb ? 12288 : 8192);
            #pragma unroll
            for (int j = 0; j < 4; ++j) {
                const int rb = (wn*64 + j*16 + lrow)*32 + lk;
                const short8 fbq = *(const short8*)&bq[rb];
                const short8 fbk = *(const short8*)&bk[rb];
                #pragma unroll
                for (int i = 0; i < 4; ++i) {
                    accq[i][j] = __builtin_amdgcn_mfma_f32_16x16x32_bf16(aq[i], fbq, accq[i][j], 0, 0, 0);
                    acck[i][j] = __builtin_amdgcn_mfma_f32_16x16x32_bf16(ak[i], fbk, acck[i][j], 0, 0, 0);
                }
            }
        }
        // lo A fragments x W-hi
        #pragma unroll
        for (int i = 0; i < 4; ++i) {
            const int r = wm*64 + i*16 + lrow;
            aq[i] = *(const short8*)&AsL[r*32 + lk];
            ak[i] = *(const short8*)&AsL[(r+1)*32 + lk];
        }
        #pragma unroll
        for (int j = 0; j < 4; ++j) {
            const int rb = (wn*64 + j*16 + lrow)*32 + lk;
            const short8 fbq = *(const short8*)&Bs[rb];          // qH
            const short8 fbk = *(const short8*)&Bs[8192 + rb];   // kH
            #pragma unroll
            for (int i = 0; i < 4; ++i) {
                accq[i][j] = __builtin_amdgcn_mfma_f32_16x16x32_bf16(aq[i], fbq, accq[i][j], 0, 0, 0);
                acck[i][j] = __builtin_amdgcn_mfma_f32_16x16x32_bf16(ak[i], fbk, acck[i][j], 0, 0, 0);
            }
        }
        __syncthreads();
    }

    // ---- epilogue: per-row dot/qn/kn over this WG's 128 cols, then atomics ----
    #pragma unroll
    for (int i = 0; i < 4; ++i) {
        #pragma unroll
        for (int reg = 0; reg < 4; ++reg) {
            float d = 0.f, qq = 0.f, kk = 0.f;
            #pragma unroll
            for (int j = 0; j < 4; ++j) {
                const float qv = accq[i][j][reg];
                const float kv = acck[i][j][reg];
                d  += qv * kv;
                qq += qv * qv;
                kk += kv * kv;
            }
            #pragma unroll
            for (int m = 1; m <= 8; m <<= 1) {
                d  += __shfl_xor(d,  m);
                qq += __shfl_xor(qq, m);
                kk += __shfl_xor(kk, m);
            }
            if ((lane & 15) == 0) {
                const int row = t0 + wm*64 + i*16 + ((lane >> 4) << 2) + reg;
                atomicAdd(&parts[row],          d);
                atomicAdd(&parts[Mtot + row],   qq);
                atomicAdd(&parts[2*Mtot + row], kk);
            }
        }
    }
}

// ---------------------------------------------------------------------------
// finalize cos + flag near-boundary tokens (|cos| < 3e-5) for exact repair
// ---------------------------------------------------------------------------
__global__ __launch_bounds__(256)
void cos_fin_kernel(const float* __restrict__ parts,
                    float* __restrict__ cosv,
                    int* __restrict__ flags)
{
    const int t = blockIdx.x*256 + threadIdx.x;
    if (t >= Mtot) return;
    const float dot = parts[t];
    const float qn  = parts[Mtot + t];
    const float kn  = parts[2*Mtot + t];
    const float c = dot / (fmaxf(sqrtf(qn), 1e-12f) * fmaxf(sqrtf(kn), 1e-12f));
    cosv[t] = c;
    if (fabsf(c) < 3e-5f && (t & (Lc-1)) != (Lc-1)) {
        const int idx = atomicAdd(flags, 1);
        if (idx < 4096) flags[1 + idx] = t;
    }
}

// exact fp32 recompute of cos for flagged tokens (one WG per token)
__global__ __launch_bounds__(256)
void repair_kernel(const float* __restrict__ X,
                   const float* __restrict__ Qw,
                   const float* __restrict__ Kw,
                   const int* __restrict__ flags,
                   float* __restrict__ cosv)
{
    __shared__ __align__(16) float x0[Dc];
    __shared__ __align__(16) float x1[Dc];
    __shared__ float rbuf[12];
    const int tid = threadIdx.x;
    const int count = min(flags[0], 4096);
    for (int fi = blockIdx.x; fi < count; fi += gridDim.x) {
        const int t = flags[1 + fi];
        {
            const int i = tid;   // 256 threads x float4 = 1024 floats
            *(float4*)&x0[i*4] = *(const float4*)&X[(size_t)t*Dc + i*4];
            *(float4*)&x1[i*4] = *(const float4*)&X[(size_t)(t+1)*Dc + i*4];
        }
        __syncthreads();
        float d = 0.f, qq = 0.f, kk = 0.f;
        #pragma unroll
        for (int jr = 0; jr < 4; ++jr) {
            const int n = tid*4 + jr;
            const float* qrow = Qw + (size_t)n*Dc;
            const float* krow = Kw + (size_t)n*Dc;
            float sq = 0.f, sk = 0.f;
            for (int k = 0; k < 256; ++k) {
                const float4 qv = *(const float4*)&qrow[k*4];
                const float4 kv = *(const float4*)&krow[k*4];
                const float4 a0 = *(const float4*)&x0[k*4];
                const float4 a1 = *(const float4*)&x1[k*4];
                sq += qv.x*a0.x + qv.y*a0.y + qv.z*a0.z + qv.w*a0.w;
                sk += kv.x*a1.x + kv.y*a1.y + kv.z*a1.z + kv.w*a1.w;
            }
            d += sq*sk; qq += sq*sq; kk += sk*sk;
        }
        #pragma unroll
        for (int m = 1; m < 64; m <<= 1) {
            d += __shfl_xor(d, m); qq += __shfl_xor(qq, m); kk += __shfl_xor(kk, m);
        }
        if ((tid & 63) == 0) {
            const int w = tid >> 6;
            rbuf[w*3+0] = d; rbuf[w*3+1] = qq; rbuf[w*3+2] = kk;
        }
        __syncthreads();
        if (tid == 0) {
            const float D = rbuf[0]+rbuf[3]+rbuf[6]+rbuf[9];
            const float Q = rbuf[1]+rbuf[4]+rbuf[7]+rbuf[10];
            const float K = rbuf[2]+rbuf[5]+rbuf[8]+rbuf[11];
            cosv[t] = D / (fmaxf(sqrtf(Q), 1e-12f) * fmaxf(sqrtf(K), 1e-12f));
        }
        __syncthreads();
    }
}

// ---------------------------------------------------------------------------
// EMA scan (round-1-verified structure)
// ---------------------------------------------------------------------------
__device__ inline void build_seg_masks(const float* __restrict__ cosv,
                                       int b, int l0, float* dec, int* msk)
{
    const int tid = threadIdx.x;
    if (tid < SEGLEN) {
        const int l = l0 + tid;
        float p;
        if (l == 0) {
            p = 1.f;
        } else {
            const float c = cosv[b*Lc + l - 1];
            p = (1.f - c) * 0.5f;
            p = fminf(fmaxf(p, 0.f), 1.f);
        }
        dec[tid] = 1.f - p;
        msk[tid] = (p > 0.5f) ? 1 : 0;
    }
    __syncthreads();
}

__global__ __launch_bounds__(256)
void seg_pass1_kernel(const float* __restrict__ X,
                      const float* __restrict__ cosv,
                      float* __restrict__ Aseg,
                      float* __restrict__ Bseg)
{
    __shared__ float dec[SEGLEN];
    __shared__ int   msk[SEGLEN];
    const int tid = threadIdx.x;
    const int b = blockIdx.x >> 6;
    const int s = blockIdx.x & 63;
    const int l0 = s * SEGLEN;
    build_seg_masks(cosv, b, l0, dec, msk);

    float4 st = make_float4(0.f, 0.f, 0.f, 0.f);
    float A = 1.f;
    const float* xb = X + (size_t)(b*Lc + l0)*Dc + tid*4;
    for (int i = 0; i < SEGLEN; i++) {
        if (msk[i]) {
            const float d = dec[i];
            const float w = 1.f - d;
            const float4 xv = *(const float4*)(xb + (size_t)i*Dc);
            st.x = d*st.x + w*xv.x;
            st.y = d*st.y + w*xv.y;
            st.z = d*st.z + w*xv.z;
            st.w = d*st.w + w*xv.w;
            A *= d;
        }
    }
    *(float4*)&Bseg[(size_t)blockIdx.x*Dc + tid*4] = st;
    if (tid == 0) Aseg[blockIdx.x] = A;
}

__global__ __launch_bounds__(256)
void seg_combine_kernel(const float* __restrict__ Aseg,
                        const float* __restrict__ Bseg,
                        const float* __restrict__ init_state,
                        float* __restrict__ carry)
{
    const int tid = threadIdx.x;
    const int b = blockIdx.x;
    float4 c = *(const float4*)&init_state[(size_t)b*Dc + tid*4];
    for (int s = 0; s < NSEG; s++) {
        const size_t idx = (size_t)(b*NSEG + s);
        *(float4*)&carry[idx*Dc + tid*4] = c;
        const float a = Aseg[idx];
        const float4 Bv = *(const float4*)&Bseg[idx*Dc + tid*4];
        c.x = a*c.x + Bv.x;
        c.y = a*c.y + Bv.y;
        c.z = a*c.z + Bv.z;
        c.w = a*c.w + Bv.w;
    }
}

__global__ __launch_bounds__(256)
void seg_pass2_kernel(const float* __restrict__ X,
                      const float* __restrict__ RES,
                      const float* __restrict__ cosv,
                      const float* __restrict__ carry,
                      float* __restrict__ OUT)
{
    __shared__ float dec[SEGLEN];
    __shared__ int   msk[SEGLEN];
    const int tid = threadIdx.x;
    const int b = blockIdx.x >> 6;
    const int s = blockIdx.x & 63;
    const int l0 = s * SEGLEN;
    build_seg_masks(cosv, b, l0, dec, msk);

    float4 st = *(const float4*)&carry[(size_t)blockIdx.x*Dc + tid*4];
    const size_t base = (size_t)(b*Lc + l0)*Dc + tid*4;
    const float* xb = X   + base;
    const float* rb = RES + base;
    float*       ob = OUT + base;
    for (int i = 0; i < SEGLEN; i++) {
        if (msk[i]) {
            const float d = dec[i];
            const float w = 1.f - d;
            const float4 xv = *(const float4*)(xb + (size_t)i*Dc);
            st.x = d*st.x + w*xv.x;
            st.y = d*st.y + w*xv.y;
            st.z = d*st.z + w*xv.z;
            st.w = d*st.w + w*xv.w;
        }
        const float4 rv = *(const float4*)(rb + (size_t)i*Dc);
        float4 ov;
        ov.x = rv.x + st.x;
        ov.y = rv.y + st.y;
        ov.z = rv.z + st.z;
        ov.w = rv.w + st.w;
        *(float4*)(ob + (size_t)i*Dc) = ov;
    }
}

// ---------------------------------------------------------------------------
extern "C" void kernel_launch(void* const* d_in, const int* in_sizes, int n_in,
                              void* d_out, int out_size, void* d_ws, size_t ws_size,
                              hipStream_t stream)
{
    const float* X    = (const float*)d_in[0];
    const float* RES  = (const float*)d_in[1];
    const float* QW   = (const float*)d_in[2];
    const float* KW   = (const float*)d_in[3];
    const float* INIT = (const float*)d_in[4];
    float* OUT = (float*)d_out;

    char* ws = (char*)d_ws;
    us*    Qhi  = (us*)   (ws + OFF_QHI);
    us*    Qlo  = (us*)   (ws + OFF_QLO);
    us*    Khi  = (us*)   (ws + OFF_KHI);
    us*    Klo  = (us*)   (ws + OFF_KLO);
    float* parts = (float*)(ws + OFF_PARTS);
    int*   flags = (int*)  (ws + OFF_FLAGS);
    float* cosv  = (float*)(ws + OFF_COSV);
    float* Aseg  = (float*)(ws + OFF_ASEG);
    float* Bseg  = (float*)(ws + OFF_BSEG);
    float* carry = (float*)(ws + OFF_CARRY);

    zero_kernel     <<<192,  256, 0, stream>>>(parts, flags);
    convert_w_kernel<<<1024, 256, 0, stream>>>(QW, Qhi, Qlo);
    convert_w_kernel<<<1024, 256, 0, stream>>>(KW, Khi, Klo);
    gemm_cos_kernel <<<1024, 256, 0, stream>>>(X, Qhi, Qlo, Khi, Klo, parts);
    cos_fin_kernel  <<<64,   256, 0, stream>>>(parts, cosv, flags);
    repair_kernel   <<<64,   256, 0, stream>>>(X, QW, KW, flags, cosv);
    seg_pass1_kernel  <<<Bc*NSEG, 256, 0, stream>>>(X, cosv, Aseg, Bseg);
    seg_combine_kernel<<<Bc,      256, 0, stream>>>(Aseg, Bseg, INIT, carry);
    seg_pass2_kernel  <<<Bc*NSEG, 256, 0, stream>>>(X, RES, cosv, carry, OUT);
}